// Round 5
// baseline (17.720 us; speedup 1.0000x reference)
//
#include <hip/hip_runtime.h>
#include <math.h>

#define M_CP   256
#define N_PTS  32768
#define BATCH  4

// composable_kernel trick: cast generic pointer to constant address space (4)
// so uniform-index loads select s_load (SGPR destination, scalar cache pipe).
#define CONST_AS __attribute__((address_space(4)))
template <typename T>
__device__ __forceinline__ T CONST_AS* cast_to_constant(T* p)
{
    return (T CONST_AS*)p;  // c-style cast across address spaces (CK idiom)
}

// 512 threads = 8 waves. Lower 4 waves: m in [0,128); upper 4: m in [128,256).
// Each half covers the block's 256 dense points. Partials of the upper half
// reduced through 3 KB LDS. Grid 512 blocks -> 2 blocks/CU -> 4 waves/SIMD.
// Inner loop reads control-point data ONLY from SGPRs (s_load): zero LDS,
// zero per-lane VMEM in the loop -> pure VALU pipe.
__global__ __launch_bounds__(512) void rbf_tps_kernel(
    const float* __restrict__ sparse_disp,   // (B, M, 3)
    const float* __restrict__ original_cp,   // (B, M, 3)
    const float* __restrict__ original_dense,// (B, N, 3)
    float* __restrict__ out)                 // (B, N, 3)
{
    __shared__ float red[256][3];

    const int t = threadIdx.x;
    const int b     = blockIdx.x >> 7;            // 128 blocks per batch
    const int nbase = (blockIdx.x & 127) * 256;
    const int i     = t & 255;                    // point index within block
    // wave-uniform m-chunk id; readfirstlane makes it PROVABLY uniform so the
    // constant-AS loads below scalarize to s_load.
    const int half  = __builtin_amdgcn_readfirstlane(t >> 8);

    const float CONST_AS* cp = cast_to_constant(
        original_cp + ((size_t)b * M_CP + half * 128) * 3);
    const float CONST_AS* sd = cast_to_constant(
        sparse_disp + ((size_t)b * M_CP + half * 128) * 3);

    const int n = nbase + i;
    const float* dp = original_dense + ((size_t)b * N_PTS + n) * 3;
    const float px = dp[0], py = dp[1], pz = dp[2];

    float ax = 0.f, ay = 0.f, az = 0.f;

    // K_ref = r^2*ln(r+1e-6) ~= r^2*(ln2/2)*log2(r^2); ln2/2 applied at store.
    #pragma unroll 8
    for (int m = 0; m < 128; ++m) {
        float cx = cp[m * 3 + 0];   // s_load -> SGPR
        float cy = cp[m * 3 + 1];
        float cz = cp[m * 3 + 2];
        float dx = px - cx;
        float dy = py - cy;
        float dz = pz - cz;
        float r2 = fmaf(dx, dx, fmaf(dy, dy, dz * dz));
        r2 = fmaxf(r2, 1e-20f);               // guard log(0)
        float K  = r2 * __log2f(r2);
        ax = fmaf(K, sd[m * 3 + 0], ax);      // SGPR second operand
        ay = fmaf(K, sd[m * 3 + 1], ay);
        az = fmaf(K, sd[m * 3 + 2], az);
    }

    if (half == 1) {
        red[i][0] = ax; red[i][1] = ay; red[i][2] = az;
    }
    __syncthreads();
    if (half == 0) {
        const float k = 0.34657359027997264f; // 0.5 * ln(2)
        float* op = out + ((size_t)b * N_PTS + n) * 3;
        op[0] = (ax + red[i][0]) * k;
        op[1] = (ay + red[i][1]) * k;
        op[2] = (az + red[i][2]) * k;
    }
}

extern "C" void kernel_launch(void* const* d_in, const int* in_sizes, int n_in,
                              void* d_out, int out_size, void* d_ws, size_t ws_size,
                              hipStream_t stream) {
    const float* sparse_disp    = (const float*)d_in[0];
    const float* original_cp    = (const float*)d_in[1];
    const float* original_dense = (const float*)d_in[2];
    float* out = (float*)d_out;

    dim3 grid(BATCH * (N_PTS / 256));   // 512 blocks
    dim3 block(512);
    rbf_tps_kernel<<<grid, block, 0, stream>>>(sparse_disp, original_cp,
                                               original_dense, out);
}

// Round 6
// 13.732 us; speedup vs baseline: 1.2904x; 1.2904x over previous
//
#include <hip/hip_runtime.h>
#include <math.h>

#define M_CP   256
#define N_PTS  32768
#define BATCH  4

// CK idiom: constant address space cast so uniform-index loads select s_load.
#define CONST_AS __attribute__((address_space(4)))
template <typename T>
__device__ __forceinline__ const T CONST_AS* cast_to_constant(const T* p)
{
    return (const T CONST_AS*)p;
}

// Block = 1024 threads (16 waves), grid = 256 blocks -> 1 block/CU,
// 4 waves/SIMD. q = t>>8 selects m-quarter [q*64, q*64+64); i = t&255
// selects the point pair (nbase+i, nbase+256+i). Partials reduced via LDS.
//
// K_ref = r^2*ln(r+1e-6) ~= r^2*(ln2/2)*log2(r^2), ln2/2 applied at store.
// Expanded form: r^2 = (|p|^2 + |c|^2 + eps) - 2p.c ; cc=|c|^2+eps staged in
// LDS (b128/4m), cp & sd consumed from SGPRs (s_load) -> 8 VALU + 1 trans
// per pair, no fmax guard needed.
__global__ __launch_bounds__(1024) void rbf_tps_kernel(
    const float* __restrict__ sparse_disp,   // (B, M, 3)
    const float* __restrict__ original_cp,   // (B, M, 3)
    const float* __restrict__ original_dense,// (B, N, 3)
    float* __restrict__ out)                 // (B, N, 3)
{
    __shared__ float cc_eps[M_CP];
    __shared__ float red[3][256][6];

    const int t = threadIdx.x;
    const int b     = blockIdx.x >> 6;        // 64 blocks per batch
    const int nbase = (blockIdx.x & 63) * 512;
    const int i     = t & 255;
    const int q     = __builtin_amdgcn_readfirstlane(t >> 8);  // wave-uniform

    // Stage cc = |c|^2 + eps (eps guards log(<=0) under fma cancellation).
    if (t < M_CP) {
        const float* c = original_cp + ((size_t)b * M_CP + t) * 3;
        float cx = c[0], cy = c[1], cz = c[2];
        cc_eps[t] = fmaf(cx, cx, fmaf(cy, cy, cz * cz)) + 1e-5f;
    }
    __syncthreads();

    const int n0 = nbase + i;
    const int n1 = nbase + 256 + i;
    const float* dp0 = original_dense + ((size_t)b * N_PTS + n0) * 3;
    const float* dp1 = original_dense + ((size_t)b * N_PTS + n1) * 3;
    const float px0 = dp0[0], py0 = dp0[1], pz0 = dp0[2];
    const float px1 = dp1[0], py1 = dp1[1], pz1 = dp1[2];
    const float pp0 = fmaf(px0, px0, fmaf(py0, py0, pz0 * pz0));
    const float pp1 = fmaf(px1, px1, fmaf(py1, py1, pz1 * pz1));
    const float m2x0 = -2.f * px0, m2y0 = -2.f * py0, m2z0 = -2.f * pz0;
    const float m2x1 = -2.f * px1, m2y1 = -2.f * py1, m2z1 = -2.f * pz1;

    const float CONST_AS* cp = cast_to_constant(
        original_cp + ((size_t)b * M_CP + q * 64) * 3);
    const float CONST_AS* sd = cast_to_constant(
        sparse_disp + ((size_t)b * M_CP + q * 64) * 3);

    float ax0 = 0.f, ay0 = 0.f, az0 = 0.f;
    float ax1 = 0.f, ay1 = 0.f, az1 = 0.f;

    #pragma unroll 2
    for (int mm = 0; mm < 64; mm += 4) {
        float4 vcc = *(const float4*)&cc_eps[q * 64 + mm];
        const float CC[4] = {vcc.x, vcc.y, vcc.z, vcc.w};

        #pragma unroll
        for (int k2 = 0; k2 < 4; ++k2) {
            const int m = mm + k2;
            float cx = cp[m * 3 + 0];          // s_load -> SGPR
            float cy = cp[m * 3 + 1];
            float cz = cp[m * 3 + 2];
            float sx = sd[m * 3 + 0];
            float sy = sd[m * 3 + 1];
            float sz = sd[m * 3 + 2];

            float r0 = fmaf(m2x0, cx, fmaf(m2y0, cy,
                       fmaf(m2z0, cz, pp0 + CC[k2])));
            float r1 = fmaf(m2x1, cx, fmaf(m2y1, cy,
                       fmaf(m2z1, cz, pp1 + CC[k2])));
            float K0 = r0 * __log2f(r0);
            float K1 = r1 * __log2f(r1);
            ax0 = fmaf(K0, sx, ax0); ay0 = fmaf(K0, sy, ay0); az0 = fmaf(K0, sz, az0);
            ax1 = fmaf(K1, sx, ax1); ay1 = fmaf(K1, sy, ay1); az1 = fmaf(K1, sz, az1);
        }
    }

    if (q != 0) {
        float* r = red[q - 1][i];
        r[0] = ax0; r[1] = ay0; r[2] = az0;
        r[3] = ax1; r[4] = ay1; r[5] = az1;
    }
    __syncthreads();

    if (q == 0) {
        #pragma unroll
        for (int w = 0; w < 3; ++w) {
            const float* r = red[w][i];
            ax0 += r[0]; ay0 += r[1]; az0 += r[2];
            ax1 += r[3]; ay1 += r[4]; az1 += r[5];
        }
        const float kk = 0.34657359027997264f;  // 0.5 * ln(2)
        float* o0 = out + ((size_t)b * N_PTS + n0) * 3;
        float* o1 = out + ((size_t)b * N_PTS + n1) * 3;
        o0[0] = ax0 * kk; o0[1] = ay0 * kk; o0[2] = az0 * kk;
        o1[0] = ax1 * kk; o1[1] = ay1 * kk; o1[2] = az1 * kk;
    }
}

extern "C" void kernel_launch(void* const* d_in, const int* in_sizes, int n_in,
                              void* d_out, int out_size, void* d_ws, size_t ws_size,
                              hipStream_t stream) {
    const float* sparse_disp    = (const float*)d_in[0];
    const float* original_cp    = (const float*)d_in[1];
    const float* original_dense = (const float*)d_in[2];
    float* out = (float*)d_out;

    dim3 grid(256);
    dim3 block(1024);
    rbf_tps_kernel<<<grid, block, 0, stream>>>(sparse_disp, original_cp,
                                               original_dense, out);
}

// Round 7
// 13.408 us; speedup vs baseline: 1.3216x; 1.0242x over previous
//
#include <hip/hip_runtime.h>
#include <math.h>

#define M_CP   256
#define N_PTS  32768
#define BATCH  4

typedef float v2f __attribute__((ext_vector_type(2)));

// CK idiom: constant address space cast so uniform-index loads select s_load.
#define CONST_AS __attribute__((address_space(4)))
template <typename T>
__device__ __forceinline__ const T CONST_AS* cast_to_constant(const T* p)
{
    return (const T CONST_AS*)p;
}

__device__ __forceinline__ v2f splat2(float s) { v2f r; r.x = s; r.y = s; return r; }

// Block = 1024 threads (16 waves), grid = 256 blocks -> 1 block/CU,
// 4 waves/SIMD. q = t>>8 selects m-quarter; i = t&255 selects the packed
// point pair (nbase+i, nbase+256+i) — both lanes of v2f, so the whole
// r^2 / K / accumulate chain runs on packed fp32 (v_pk_fma_f32 etc.),
// control-point operands from SGPRs (s_load) broadcast via op_sel.
//
// K_ref = r^2*ln(r+1e-6) ~= r^2*(ln2/2)*log2(r^2), ln2/2 applied at store.
// r^2 = (|p|^2 + |c|^2 + eps) - 2p.c ; eps=1e-5 baked into cc guards log(<=0).
__global__ __launch_bounds__(1024) void rbf_tps_kernel(
    const float* __restrict__ sparse_disp,   // (B, M, 3)
    const float* __restrict__ original_cp,   // (B, M, 3)
    const float* __restrict__ original_dense,// (B, N, 3)
    float* __restrict__ out)                 // (B, N, 3)
{
    __shared__ float cc_eps[M_CP];
    __shared__ float red[3][256][6];

    const int t = threadIdx.x;
    const int b     = blockIdx.x >> 6;        // 64 blocks per batch
    const int nbase = (blockIdx.x & 63) * 512;
    const int i     = t & 255;
    const int q     = __builtin_amdgcn_readfirstlane(t >> 8);  // wave-uniform

    if (t < M_CP) {
        const float* c = original_cp + ((size_t)b * M_CP + t) * 3;
        float cx = c[0], cy = c[1], cz = c[2];
        cc_eps[t] = fmaf(cx, cx, fmaf(cy, cy, cz * cz)) + 1e-5f;
    }
    __syncthreads();

    const int n0 = nbase + i;
    const int n1 = nbase + 256 + i;
    const float* dp0 = original_dense + ((size_t)b * N_PTS + n0) * 3;
    const float* dp1 = original_dense + ((size_t)b * N_PTS + n1) * 3;
    const float px0 = dp0[0], py0 = dp0[1], pz0 = dp0[2];
    const float px1 = dp1[0], py1 = dp1[1], pz1 = dp1[2];

    v2f ppv;  ppv.x  = fmaf(px0, px0, fmaf(py0, py0, pz0 * pz0));
              ppv.y  = fmaf(px1, px1, fmaf(py1, py1, pz1 * pz1));
    v2f m2xv; m2xv.x = -2.f * px0; m2xv.y = -2.f * px1;
    v2f m2yv; m2yv.x = -2.f * py0; m2yv.y = -2.f * py1;
    v2f m2zv; m2zv.x = -2.f * pz0; m2zv.y = -2.f * pz1;

    const float CONST_AS* cp = cast_to_constant(
        original_cp + ((size_t)b * M_CP + q * 64) * 3);
    const float CONST_AS* sd = cast_to_constant(
        sparse_disp + ((size_t)b * M_CP + q * 64) * 3);

    v2f axv = {0.f, 0.f}, ayv = {0.f, 0.f}, azv = {0.f, 0.f};

    #pragma unroll 2
    for (int mm = 0; mm < 64; mm += 4) {
        float4 vcc = *(const float4*)&cc_eps[q * 64 + mm];
        const float CC[4] = {vcc.x, vcc.y, vcc.z, vcc.w};

        #pragma unroll
        for (int k2 = 0; k2 < 4; ++k2) {
            const int m = mm + k2;
            float cx = cp[m * 3 + 0];          // s_load -> SGPR
            float cy = cp[m * 3 + 1];
            float cz = cp[m * 3 + 2];
            float sx = sd[m * 3 + 0];
            float sy = sd[m * 3 + 1];
            float sz = sd[m * 3 + 2];

            v2f r2 = ppv + splat2(CC[k2]);                         // v_pk_add
            r2 = __builtin_elementwise_fma(m2zv, splat2(cz), r2);  // v_pk_fma
            r2 = __builtin_elementwise_fma(m2yv, splat2(cy), r2);
            r2 = __builtin_elementwise_fma(m2xv, splat2(cx), r2);

            v2f l; l.x = __log2f(r2.x); l.y = __log2f(r2.y);       // 2x v_log
            v2f K = r2 * l;                                        // v_pk_mul

            axv = __builtin_elementwise_fma(K, splat2(sx), axv);
            ayv = __builtin_elementwise_fma(K, splat2(sy), ayv);
            azv = __builtin_elementwise_fma(K, splat2(sz), azv);
        }
    }

    if (q != 0) {
        float* r = red[q - 1][i];
        r[0] = axv.x; r[1] = ayv.x; r[2] = azv.x;
        r[3] = axv.y; r[4] = ayv.y; r[5] = azv.y;
    }
    __syncthreads();

    if (q == 0) {
        #pragma unroll
        for (int w = 0; w < 3; ++w) {
            const float* r = red[w][i];
            axv.x += r[0]; ayv.x += r[1]; azv.x += r[2];
            axv.y += r[3]; ayv.y += r[4]; azv.y += r[5];
        }
        const float kk = 0.34657359027997264f;  // 0.5 * ln(2)
        float* o0 = out + ((size_t)b * N_PTS + n0) * 3;
        float* o1 = out + ((size_t)b * N_PTS + n1) * 3;
        o0[0] = axv.x * kk; o0[1] = ayv.x * kk; o0[2] = azv.x * kk;
        o1[0] = axv.y * kk; o1[1] = ayv.y * kk; o1[2] = azv.y * kk;
    }
}

extern "C" void kernel_launch(void* const* d_in, const int* in_sizes, int n_in,
                              void* d_out, int out_size, void* d_ws, size_t ws_size,
                              hipStream_t stream) {
    const float* sparse_disp    = (const float*)d_in[0];
    const float* original_cp    = (const float*)d_in[1];
    const float* original_dense = (const float*)d_in[2];
    float* out = (float*)d_out;

    dim3 grid(256);
    dim3 block(1024);
    rbf_tps_kernel<<<grid, block, 0, stream>>>(sparse_disp, original_cp,
                                               original_dense, out);
}

// Round 8
// 13.135 us; speedup vs baseline: 1.3491x; 1.0208x over previous
//
#include <hip/hip_runtime.h>
#include <math.h>

#define M_CP   256
#define N_PTS  32768
#define BATCH  4

typedef float v2f __attribute__((ext_vector_type(2)));

// CK idiom: constant address space cast so uniform-index loads select s_load.
#define CONST_AS __attribute__((address_space(4)))
template <typename T>
__device__ __forceinline__ const T CONST_AS* cast_to_constant(const T* p)
{
    return (const T CONST_AS*)p;
}

__device__ __forceinline__ v2f splat2(float s) { v2f r; r.x = s; r.y = s; return r; }

// Block = 1024 threads (16 waves), grid = 512 blocks -> 2 blocks/CU ->
// 8 waves/SIMD (VGPR capped at 64 via launch_bounds). m-split 8:
// group q = t>>7 (2 waves) handles m in [q*32, q*32+32) for the block's
// 256 points; i = t&127 -> packed point pair (nbase+i, nbase+128+i) in v2f.
// Whole chain on packed fp32 (v_pk_fma_f32 etc.), control points from
// SGPRs (s_load). Shorter (32-iter) chains + 8 waves/SIMD hide s_load and
// v_log latency. Partials reduced via LDS (7 x 128 x 6 floats = 21.5 KB).
//
// K_ref = r^2*ln(r+1e-6) ~= r^2*(ln2/2)*log2(r^2), ln2/2 applied at store.
// r^2 = (|p|^2 + |c|^2 + eps) - 2p.c ; eps=1e-5 baked into cc guards log(<=0).
__global__ __launch_bounds__(1024, 8) void rbf_tps_kernel(
    const float* __restrict__ sparse_disp,   // (B, M, 3)
    const float* __restrict__ original_cp,   // (B, M, 3)
    const float* __restrict__ original_dense,// (B, N, 3)
    float* __restrict__ out)                 // (B, N, 3)
{
    __shared__ float cc_eps[M_CP];
    __shared__ float red[7][128][6];

    const int t = threadIdx.x;
    const int b     = blockIdx.x >> 7;        // 128 blocks per batch
    const int nbase = (blockIdx.x & 127) * 256;
    const int i     = t & 127;
    const int q     = __builtin_amdgcn_readfirstlane(t >> 7);  // wave-uniform

    if (t < M_CP) {
        const float* c = original_cp + ((size_t)b * M_CP + t) * 3;
        float cx = c[0], cy = c[1], cz = c[2];
        cc_eps[t] = fmaf(cx, cx, fmaf(cy, cy, cz * cz)) + 1e-5f;
    }
    __syncthreads();

    const int n0 = nbase + i;
    const int n1 = nbase + 128 + i;
    const float* dp0 = original_dense + ((size_t)b * N_PTS + n0) * 3;
    const float* dp1 = original_dense + ((size_t)b * N_PTS + n1) * 3;
    const float px0 = dp0[0], py0 = dp0[1], pz0 = dp0[2];
    const float px1 = dp1[0], py1 = dp1[1], pz1 = dp1[2];

    v2f ppv;  ppv.x  = fmaf(px0, px0, fmaf(py0, py0, pz0 * pz0));
              ppv.y  = fmaf(px1, px1, fmaf(py1, py1, pz1 * pz1));
    v2f m2xv; m2xv.x = -2.f * px0; m2xv.y = -2.f * px1;
    v2f m2yv; m2yv.x = -2.f * py0; m2yv.y = -2.f * py1;
    v2f m2zv; m2zv.x = -2.f * pz0; m2zv.y = -2.f * pz1;

    const float CONST_AS* cp = cast_to_constant(
        original_cp + ((size_t)b * M_CP + q * 32) * 3);
    const float CONST_AS* sd = cast_to_constant(
        sparse_disp + ((size_t)b * M_CP + q * 32) * 3);

    v2f axv = {0.f, 0.f}, ayv = {0.f, 0.f}, azv = {0.f, 0.f};

    #pragma unroll 2
    for (int mm = 0; mm < 32; mm += 4) {
        float4 vcc = *(const float4*)&cc_eps[q * 32 + mm];
        const float CC[4] = {vcc.x, vcc.y, vcc.z, vcc.w};

        #pragma unroll
        for (int k2 = 0; k2 < 4; ++k2) {
            const int m = mm + k2;
            float cx = cp[m * 3 + 0];          // s_load -> SGPR
            float cy = cp[m * 3 + 1];
            float cz = cp[m * 3 + 2];
            float sx = sd[m * 3 + 0];
            float sy = sd[m * 3 + 1];
            float sz = sd[m * 3 + 2];

            v2f r2 = ppv + splat2(CC[k2]);                         // v_pk_add
            r2 = __builtin_elementwise_fma(m2zv, splat2(cz), r2);  // v_pk_fma
            r2 = __builtin_elementwise_fma(m2yv, splat2(cy), r2);
            r2 = __builtin_elementwise_fma(m2xv, splat2(cx), r2);

            v2f l; l.x = __log2f(r2.x); l.y = __log2f(r2.y);       // 2x v_log
            v2f K = r2 * l;                                        // v_pk_mul

            axv = __builtin_elementwise_fma(K, splat2(sx), axv);
            ayv = __builtin_elementwise_fma(K, splat2(sy), ayv);
            azv = __builtin_elementwise_fma(K, splat2(sz), azv);
        }
    }

    if (q != 0) {
        float* r = red[q - 1][i];
        r[0] = axv.x; r[1] = ayv.x; r[2] = azv.x;
        r[3] = axv.y; r[4] = ayv.y; r[5] = azv.y;
    }
    __syncthreads();

    if (q == 0) {
        #pragma unroll
        for (int w = 0; w < 7; ++w) {
            const float* r = red[w][i];
            axv.x += r[0]; ayv.x += r[1]; azv.x += r[2];
            axv.y += r[3]; ayv.y += r[4]; azv.y += r[5];
        }
        const float kk = 0.34657359027997264f;  // 0.5 * ln(2)
        float* o0 = out + ((size_t)b * N_PTS + n0) * 3;
        float* o1 = out + ((size_t)b * N_PTS + n1) * 3;
        o0[0] = axv.x * kk; o0[1] = ayv.x * kk; o0[2] = azv.x * kk;
        o1[0] = axv.y * kk; o1[1] = ayv.y * kk; o1[2] = azv.y * kk;
    }
}

extern "C" void kernel_launch(void* const* d_in, const int* in_sizes, int n_in,
                              void* d_out, int out_size, void* d_ws, size_t ws_size,
                              hipStream_t stream) {
    const float* sparse_disp    = (const float*)d_in[0];
    const float* original_cp    = (const float*)d_in[1];
    const float* original_dense = (const float*)d_in[2];
    float* out = (float*)d_out;

    dim3 grid(512);
    dim3 block(1024);
    rbf_tps_kernel<<<grid, block, 0, stream>>>(sparse_disp, original_cp,
                                               original_dense, out);
}